// Round 3
// baseline (421.967 us; speedup 1.0000x reference)
//
#include <hip/hip_runtime.h>
#include <hip/hip_bf16.h>

// B=4, S=2048, D=1024; fp32 in/out, bf16 MFMA compute.
// GEMM engine: 256x256 tile, BK=64, 8 waves, 8-phase schedule with
// one-phase-ahead register pipelining, counted vmcnt, 1 barrier/phase.
#define SS 2048
#define DD 1024
#define NB 4

typedef __attribute__((ext_vector_type(8))) short  bf8;    // 8 x bf16
typedef __attribute__((ext_vector_type(4))) float  f32x4;

static __device__ __forceinline__ unsigned short f2bf(float f) {
    unsigned u = __float_as_uint(f);
    u += 0x7fffu + ((u >> 16) & 1u);
    return (unsigned short)(u >> 16);
}

static __device__ __forceinline__ void gload_lds16(const void* g, void* lds) {
    __builtin_amdgcn_global_load_lds((__attribute__((address_space(1))) void*)g,
                                     (__attribute__((address_space(3))) void*)lds,
                                     16, 0, 0);
}

#define BAR()   __builtin_amdgcn_s_barrier()
#define VMW(N)  asm volatile("s_waitcnt vmcnt(" #N ")" ::: "memory")
#define P1()    __builtin_amdgcn_s_setprio(1)
#define P0()    __builtin_amdgcn_s_setprio(0)

#define QUAD(FM0, FN0, AF, BF) \
  { _Pragma("unroll") for (int ks = 0; ks < 2; ++ks) { \
      _Pragma("unroll") for (int i2 = 0; i2 < 4; ++i2) { \
        _Pragma("unroll") for (int j2 = 0; j2 < 2; ++j2) { \
          acc[FM0 + i2][FN0 + j2] = __builtin_amdgcn_mfma_f32_16x16x32_bf16( \
              AF[i2][ks], BF[j2][ks], acc[FM0 + i2][FN0 + j2], 0, 0, 0); } } } }

#define LDA4(buf, fmb, d) \
  { _Pragma("unroll") for (int i2 = 0; i2 < 4; ++i2) { \
      d[i2][0] = rdA(buf, (fmb) + i2, 0); d[i2][1] = rdA(buf, (fmb) + i2, 1); } }
#define LDB2(buf, fnb, d) \
  { _Pragma("unroll") for (int j2 = 0; j2 < 2; ++j2) { \
      d[j2][0] = rdB(buf, (fnb) + j2, 0); d[j2][1] = rdB(buf, (fnb) + j2, 1); } }

// ---------------- fp32 -> bf16 converts ----------------
__global__ __launch_bounds__(256)
void cvt3(const float* __restrict__ a, const float* __restrict__ b, const float* __restrict__ c,
          unsigned short* __restrict__ oa, unsigned short* __restrict__ ob,
          unsigned short* __restrict__ oc, int n4) {
    int i = blockIdx.x * 256 + threadIdx.x;
    if (i >= n4) return;
    const float* in = blockIdx.y == 0 ? a : blockIdx.y == 1 ? b : c;
    unsigned short* out = blockIdx.y == 0 ? oa : blockIdx.y == 1 ? ob : oc;
    float4 v = ((const float4*)in)[i];
    ushort4 o;
    o.x = f2bf(v.x); o.y = f2bf(v.y); o.z = f2bf(v.z); o.w = f2bf(v.w);
    ((ushort4*)out)[i] = o;
}

// ---------------- 256^2 pipelined bt-GEMM ----------------
// MODE 0: merged QKV projections (z selects; z==2 stores transposed [b][d][s])
// MODE 2: scores = Q.K^T/32, fp32, causal tile skip
// MODE 3: PV, fp32 out, causal K-limit, split-K (atomicAdd) for large q-tiles
template<int MODE>
__global__ __launch_bounds__(512, 2)
void gemm256(const unsigned short* __restrict__ A0p, const unsigned short* __restrict__ B0w,
             const float* __restrict__ bias0, void* __restrict__ C0,
             const unsigned short* __restrict__ A1p, const unsigned short* __restrict__ B1w,
             const float* __restrict__ bias1, void* __restrict__ C1,
             const unsigned short* __restrict__ A2p, const unsigned short* __restrict__ B2w,
             const float* __restrict__ bias2, void* __restrict__ C2)
{
    constexpr int LDA = (MODE == 3) ? 2048 : 1024;
    constexpr int LDB = (MODE == 3) ? 2048 : 1024;
    const int bx = blockIdx.x, by = blockIdx.y, bz = blockIdx.z;
    if (MODE == 2 && bx > by) return;

    const unsigned short* A;
    const unsigned short* Bm;
    const float* bias = nullptr;
    int len, qy = 0, seg = 0, nsp = 1;
    if (MODE == 0) {
        A    = (bz == 0 ? A0p : bz == 1 ? A1p : A2p) + (size_t)by * 256 * LDA;
        Bm   = (bz == 0 ? B0w : bz == 1 ? B1w : B2w) + (size_t)bx * 256 * LDB;
        bias = bz == 0 ? bias0 : bz == 1 ? bias1 : bias2;
        len  = 1024;
    } else if (MODE == 2) {
        A   = A0p + (size_t)bz * SS * DD + (size_t)by * 256 * LDA;
        Bm  = B0w + (size_t)bz * SS * DD + (size_t)bx * 256 * LDB;
        len = 1024;
    } else {
        if (by < 4) { qy = by; seg = 0; nsp = 1; }
        else        { qy = 4 + ((by - 4) >> 1); seg = (by - 4) & 1; nsp = 2; }
        int ktot = (qy + 1) * 256, halfk = ktot >> 1;
        int kst = seg ? halfk : 0;
        len = (nsp == 1) ? ktot : halfk;
        A  = A0p + (size_t)bz * SS * SS + (size_t)qy * 256 * LDA + kst;
        Bm = B0w + (size_t)bz * DD * SS + (size_t)bx * 256 * LDB + kst;
    }

    extern __shared__ __align__(16) char lds[];
    const int tid = threadIdx.x;
    const int l = tid & 63, w = tid >> 6;
    const int wr = w >> 2, wc = w & 3;

    // stage one half-tile (2 x gload16/thread); LDS dest linear; global src
    // pre-swizzled (slot = col ^ (row&7)) so swizzled reads see linear data
    auto stg = [&](const unsigned short* src, int ld, char* mb, int half, int tile) {
        #pragma unroll
        for (int j = 0; j < 2; ++j) {
            int rr = half * 128 + (w * 2 + j) * 8 + (l >> 3);
            int cc = (l & 7) ^ (l >> 3);
            gload_lds16(src + (size_t)rr * ld + tile * 64 + cc * 8,
                        mb + half * 16384 + (w * 2 + j) * 1024);
        }
    };
    auto rdA = [&](int buf, int fm, int ks) -> bf8 {
        int row = wr * 128 + fm * 16 + (l & 15);
        return *(const bf8*)(lds + buf * 65536 + row * 128 +
                             ((((ks << 2) + (l >> 4)) ^ (l & 7)) << 4));
    };
    auto rdB = [&](int buf, int fn, int ks) -> bf8 {
        int row = wc * 64 + fn * 16 + (l & 15);
        return *(const bf8*)(lds + buf * 65536 + 32768 + row * 128 +
                             ((((ks << 2) + (l >> 4)) ^ (l & 7)) << 4));
    };

    char* A0b = lds;                 char* B0b = lds + 32768;
    char* A1b = lds + 65536;         char* B1b = lds + 98304;

    f32x4 acc[8][4];
    #pragma unroll
    for (int i2 = 0; i2 < 8; ++i2)
        #pragma unroll
        for (int j2 = 0; j2 < 4; ++j2) acc[i2][j2] = (f32x4){0.f, 0.f, 0.f, 0.f};

    bf8 aA0[4][2], aA1[4][2], aB[4][2], bL[2][2], bH[2][2];

    const int NT = len >> 6;        // K-tiles of 64 (always even, >= 4)
    const int NITER = NT >> 1;

    // prologue: stage tile0 (A,B) + tile1 (A both halves, B h0)
    stg(A, LDA, A0b, 0, 0);  stg(A, LDA, A0b, 1, 0);
    stg(Bm, LDB, B0b, 0, 0); stg(Bm, LDB, B0b, 1, 0);
    stg(A, LDA, A1b, 0, 1);  stg(A, LDA, A1b, 1, 1);
    stg(Bm, LDB, B1b, 0, 1);
    VMW(6); BAR();
    LDA4(0, 0, aA0); LDB2(0, 0, bL);   // frags for phase 0 (tile 0)

    for (int it = 0; it < NITER - 1; ++it) {
        const int tO = 2 * it + 1, tE2 = 2 * it + 2, tO2 = 2 * it + 3;
        // p0: compute E(0,0); load aB(E); finish staging tile tO
        LDA4(0, 4, aB);
        stg(Bm, LDB, B1b, 1, tO);
        P1(); QUAD(0, 0, aA0, bL); P0(); BAR();
        // p1: compute E(4,0); load bH(E); stage A(tE2) h0
        LDB2(0, 2, bH);
        stg(A, LDA, A0b, 0, tE2);
        P1(); QUAD(4, 0, aB, bL); P0(); BAR();
        // p2: compute E(4,2); stage A(tE2) h1; ensure tile tO landed
        stg(A, LDA, A0b, 1, tE2);
        P1(); QUAD(4, 2, aB, bH); P0(); VMW(4); BAR();
        // p3: compute E(0,2); load aA1,bL (tile tO); stage B(tE2) h0
        LDA4(1, 0, aA1); LDB2(1, 0, bL);
        stg(Bm, LDB, B0b, 0, tE2);
        P1(); QUAD(0, 2, aA0, bH); P0(); BAR();
        // p4: compute O(0,0); load aB(O); stage B(tE2) h1
        LDA4(1, 4, aB);
        stg(Bm, LDB, B0b, 1, tE2);
        P1(); QUAD(0, 0, aA1, bL); P0(); BAR();
        // p5: compute O(4,0); load bH(O); stage A(tO2) h0
        LDB2(1, 2, bH);
        stg(A, LDA, A1b, 0, tO2);
        P1(); QUAD(4, 0, aB, bL); P0(); BAR();
        // p6: compute O(4,2); stage A(tO2) h1; ensure tile tE2 landed
        stg(A, LDA, A1b, 1, tO2);
        P1(); QUAD(4, 2, aB, bH); P0(); VMW(4); BAR();
        // p7: compute O(0,2); load aA0,bL (tile tE2); stage B(tO2) h0
        LDA4(0, 0, aA0); LDB2(0, 0, bL);
        stg(Bm, LDB, B1b, 0, tO2);
        P1(); QUAD(0, 2, aA1, bH); P0(); BAR();
    }

    // ---- peeled tail: tiles NT-2 (buf0), NT-1 (buf1) ----
    {
        const int tO = NT - 1;
        LDA4(0, 4, aB);
        stg(Bm, LDB, B1b, 1, tO);
        P1(); QUAD(0, 0, aA0, bL); P0(); BAR();
        LDB2(0, 2, bH);
        P1(); QUAD(4, 0, aB, bL); P0(); BAR();
        P1(); QUAD(4, 2, aB, bH); P0(); VMW(0); BAR();
        LDA4(1, 0, aA1); LDB2(1, 0, bL);
        P1(); QUAD(0, 2, aA0, bH); P0(); BAR();
        LDA4(1, 4, aB);
        P1(); QUAD(0, 0, aA1, bL); P0(); BAR();
        LDB2(1, 2, bH);
        P1(); QUAD(4, 0, aB, bL); P0(); BAR();
        P1(); QUAD(4, 2, aB, bH); P0(); BAR();
        P1(); QUAD(0, 2, aA1, bH); P0();
    }

    // ---- epilogue ----
    const int mb0 = ((MODE == 3) ? qy * 256 : by * 256) + wr * 128;
    const int nb0 = bx * 256 + wc * 64;
    if (MODE == 0) {
        float bv[4];
        #pragma unroll
        for (int fn = 0; fn < 4; ++fn) bv[fn] = bias[nb0 + fn * 16 + (l & 15)];
        if (bz < 2) {
            unsigned short* C = (unsigned short*)(bz == 0 ? C0 : C1);
            #pragma unroll
            for (int fm = 0; fm < 8; ++fm) {
                int m0 = mb0 + fm * 16 + ((l >> 4) << 2);
                #pragma unroll
                for (int fn = 0; fn < 4; ++fn) {
                    int n = nb0 + fn * 16 + (l & 15);
                    #pragma unroll
                    for (int r = 0; r < 4; ++r)
                        C[(size_t)(m0 + r) * DD + n] = f2bf(acc[fm][fn][r] + bv[fn]);
                }
            }
        } else {
            unsigned short* C = (unsigned short*)C2;
            int batch = (by * 256) >> 11;
            int sbase = by * 256 - batch * SS + wr * 128;
            #pragma unroll
            for (int fm = 0; fm < 8; ++fm) {
                int s0 = sbase + fm * 16 + ((l >> 4) << 2);
                #pragma unroll
                for (int fn = 0; fn < 4; ++fn) {
                    int n = nb0 + fn * 16 + (l & 15);
                    ushort4 pk;
                    pk.x = f2bf(acc[fm][fn][0] + bv[fn]);
                    pk.y = f2bf(acc[fm][fn][1] + bv[fn]);
                    pk.z = f2bf(acc[fm][fn][2] + bv[fn]);
                    pk.w = f2bf(acc[fm][fn][3] + bv[fn]);
                    *(ushort4*)&C[(size_t)batch * DD * SS + (size_t)n * SS + s0] = pk;
                }
            }
        }
    } else if (MODE == 2) {
        float* C = (float*)C0 + (size_t)bz * SS * SS;
        #pragma unroll
        for (int fm = 0; fm < 8; ++fm) {
            int m0 = mb0 + fm * 16 + ((l >> 4) << 2);
            #pragma unroll
            for (int fn = 0; fn < 4; ++fn) {
                int n = nb0 + fn * 16 + (l & 15);
                #pragma unroll
                for (int r = 0; r < 4; ++r)
                    C[(size_t)(m0 + r) * SS + n] = acc[fm][fn][r] * 0.03125f;
            }
        }
    } else {
        float* C = (float*)C0 + (size_t)bz * SS * DD;
        #pragma unroll
        for (int fm = 0; fm < 8; ++fm) {
            int m0 = mb0 + fm * 16 + ((l >> 4) << 2);
            #pragma unroll
            for (int fn = 0; fn < 4; ++fn) {
                int n = nb0 + fn * 16 + (l & 15);
                if (nsp == 1) {
                    #pragma unroll
                    for (int r = 0; r < 4; ++r)
                        C[(size_t)(m0 + r) * DD + n] = acc[fm][fn][r];
                } else {
                    #pragma unroll
                    for (int r = 0; r < 4; ++r)
                        atomicAdd(&C[(size_t)(m0 + r) * DD + n], acc[fm][fn][r]);
                }
            }
        }
    }
}

// ---------------- causal row softmax: fp32 scores -> bf16 P ----------------
__global__ __launch_bounds__(256)
void softmax_causal(const float* __restrict__ Sb, unsigned short* __restrict__ P) {
    __shared__ float tmp[8];
    int row = blockIdx.x;
    int b = row >> 11, q = row & 2047;
    const float* s = Sb + ((size_t)b * SS + q) * SS;
    unsigned short* p = P + ((size_t)b * SS + q) * SS;
    int len  = q + 1;
    int wlen = ((q >> 8) + 1) << 8;            // zero-pad to 256 for PV tiles

    float mx = -3e38f;
    for (int i = threadIdx.x; i < len; i += 256) mx = fmaxf(mx, s[i]);
    #pragma unroll
    for (int o = 32; o; o >>= 1) mx = fmaxf(mx, __shfl_xor(mx, o));
    if ((threadIdx.x & 63) == 0) tmp[threadIdx.x >> 6] = mx;
    __syncthreads();
    mx = fmaxf(fmaxf(tmp[0], tmp[1]), fmaxf(tmp[2], tmp[3]));

    float sum = 0.f;
    for (int i = threadIdx.x; i < len; i += 256) sum += __expf(s[i] - mx);
    #pragma unroll
    for (int o = 32; o; o >>= 1) sum += __shfl_xor(sum, o);
    if ((threadIdx.x & 63) == 0) tmp[4 + (threadIdx.x >> 6)] = sum;
    __syncthreads();
    sum = tmp[4] + tmp[5] + tmp[6] + tmp[7];
    float inv = 1.f / sum;

    for (int i = threadIdx.x; i < wlen; i += 256) {
        float e = (i < len) ? __expf(s[i] - mx) * inv : 0.f;
        p[i] = f2bf(e);
    }
}

// ---------------- launch ----------------
extern "C" void kernel_launch(void* const* d_in, const int* in_sizes, int n_in,
                              void* d_out, int out_size, void* d_ws, size_t ws_size,
                              hipStream_t stream) {
    constexpr size_t NX = (size_t)NB * SS * DD;
    constexpr size_t NW = (size_t)DD * DD;

    const float* q   = (const float*)d_in[0];
    const float* k   = (const float*)d_in[1];
    const float* v   = (const float*)d_in[2];
    const float* w_q = (const float*)d_in[4];
    const float* b_q = (const float*)d_in[5];
    const float* w_k = (const float*)d_in[6];
    const float* b_k = (const float*)d_in[7];
    const float* w_v = (const float*)d_in[8];
    const float* b_v = (const float*)d_in[9];
    float* out = (float*)d_out;

    char* ws = (char*)d_ws;
    size_t off = 0;
    auto take = [&](size_t bytes) { char* p = ws + off; off += (bytes + 255) & ~(size_t)255; return p; };
    unsigned short* qb  = (unsigned short*)take(NX * 2);
    unsigned short* kb  = (unsigned short*)take(NX * 2);
    unsigned short* vb  = (unsigned short*)take(NX * 2);
    unsigned short* wqb = (unsigned short*)take(NW * 2);
    unsigned short* wkb = (unsigned short*)take(NW * 2);
    unsigned short* wvb = (unsigned short*)take(NW * 2);
    unsigned short* Qp  = (unsigned short*)take(NX * 2);
    unsigned short* Kp  = (unsigned short*)take(NX * 2);
    unsigned short* VpT = (unsigned short*)take(NX * 2);   // [b][d][s]
    float*          Sb  = (float*)take((size_t)NB * SS * SS * 4);
    unsigned short* P   = qb;   // 33.5 MB: overlays dead qb+kb after projections

    dim3 blk(256);
    cvt3<<<dim3(NX / 4 / 256, 3), blk, 0, stream>>>(q, k, v, qb, kb, vb, (int)(NX / 4));
    cvt3<<<dim3(NW / 4 / 256, 3), blk, 0, stream>>>(w_q, w_k, w_v, wqb, wkb, wvb, (int)(NW / 4));
    hipMemsetAsync(d_out, 0, NB * (size_t)SS * DD * 4, stream);  // PV split-K accumulates

    constexpr size_t LDSB = 131072;
    gemm256<0><<<dim3(4, 32, 3), dim3(512), LDSB, stream>>>(
        qb, wqb, b_q, Qp,  kb, wkb, b_k, Kp,  vb, wvb, b_v, VpT);
    gemm256<2><<<dim3(8, 8, 4), dim3(512), LDSB, stream>>>(
        Qp, Kp, nullptr, Sb, nullptr, nullptr, nullptr, nullptr,
        nullptr, nullptr, nullptr, nullptr);
    softmax_causal<<<dim3(NB * SS), blk, 0, stream>>>(Sb, P);
    gemm256<3><<<dim3(4, 12, 4), dim3(512), LDSB, stream>>>(
        P, VpT, nullptr, out, nullptr, nullptr, nullptr, nullptr,
        nullptr, nullptr, nullptr, nullptr);
}

// Round 4
// 297.285 us; speedup vs baseline: 1.4194x; 1.4194x over previous
//
#include <hip/hip_runtime.h>
#include <hip/hip_bf16.h>

// B=4, S=2048, D=1024; fp32 in/out, bf16 MFMA compute.
// GEMM engine: 256x256 tile, BK=64, 8 waves (512 thr), 8-phase counted-vmcnt
// schedule (T2 swizzle + T3/T4 + T5 setprio), 128 KiB LDS double-buffer.
// R4 = R2 minus all sched_barrier(0) (m141: order-pinning costs ~40%).
#define SS 2048
#define DD 1024
#define NB 4

typedef __attribute__((ext_vector_type(8))) short  bf8;    // 8 x bf16
typedef __attribute__((ext_vector_type(4))) float  f32x4;

static __device__ __forceinline__ unsigned short f2bf(float f) {
    unsigned u = __float_as_uint(f);
    u += 0x7fffu + ((u >> 16) & 1u);
    return (unsigned short)(u >> 16);
}

static __device__ __forceinline__ void gload_lds16(const void* g, void* lds) {
    __builtin_amdgcn_global_load_lds((__attribute__((address_space(1))) void*)g,
                                     (__attribute__((address_space(3))) void*)lds,
                                     16, 0, 0);
}

#define BAR()   __builtin_amdgcn_s_barrier()
#define LGKM0() asm volatile("s_waitcnt lgkmcnt(0)" ::: "memory")
#define LGKM8() asm volatile("s_waitcnt lgkmcnt(8)" ::: "memory")
#define VMW(N)  asm volatile("s_waitcnt vmcnt(" #N ")" ::: "memory")
#define P1()    __builtin_amdgcn_s_setprio(1)
#define P0()    __builtin_amdgcn_s_setprio(0)

#define QUAD(FM0, FN0, AF, BF) \
  { _Pragma("unroll") for (int ks = 0; ks < 2; ++ks) { \
      _Pragma("unroll") for (int i2 = 0; i2 < 4; ++i2) { \
        _Pragma("unroll") for (int j2 = 0; j2 < 2; ++j2) { \
          acc[FM0 + i2][FN0 + j2] = __builtin_amdgcn_mfma_f32_16x16x32_bf16( \
              AF[i2][ks], BF[j2][ks], acc[FM0 + i2][FN0 + j2], 0, 0, 0); } } } }

#define LDA4(buf, fmb, d) \
  { _Pragma("unroll") for (int i2 = 0; i2 < 4; ++i2) { \
      d[i2][0] = rdA(buf, (fmb) + i2, 0); d[i2][1] = rdA(buf, (fmb) + i2, 1); } }
#define LDB2(buf, fnb, d) \
  { _Pragma("unroll") for (int j2 = 0; j2 < 2; ++j2) { \
      d[j2][0] = rdB(buf, (fnb) + j2, 0); d[j2][1] = rdB(buf, (fnb) + j2, 1); } }

// ---------------- fp32 -> bf16 converts ----------------
__global__ __launch_bounds__(256)
void cvt3(const float* __restrict__ a, const float* __restrict__ b, const float* __restrict__ c,
          unsigned short* __restrict__ oa, unsigned short* __restrict__ ob,
          unsigned short* __restrict__ oc, int n4) {
    int i = blockIdx.x * 256 + threadIdx.x;
    if (i >= n4) return;
    const float* in = blockIdx.y == 0 ? a : blockIdx.y == 1 ? b : c;
    unsigned short* out = blockIdx.y == 0 ? oa : blockIdx.y == 1 ? ob : oc;
    float4 v = ((const float4*)in)[i];
    ushort4 o;
    o.x = f2bf(v.x); o.y = f2bf(v.y); o.z = f2bf(v.z); o.w = f2bf(v.w);
    ((ushort4*)out)[i] = o;
}

// ---------------- 256^2 8-phase bt-GEMM ----------------
// MODE 0: merged QKV projections (z selects; z==2 stores transposed [b][d][s])
// MODE 2: scores  = Q.K^T/32, fp32, causal tile skip
// MODE 3: PV, fp32 out, causal K-limit, split-K (atomicAdd) for large q-tiles
template<int MODE>
__global__ __launch_bounds__(512, 2)
void gemm256(const unsigned short* __restrict__ A0p, const unsigned short* __restrict__ B0w,
             const float* __restrict__ bias0, void* __restrict__ C0,
             const unsigned short* __restrict__ A1p, const unsigned short* __restrict__ B1w,
             const float* __restrict__ bias1, void* __restrict__ C1,
             const unsigned short* __restrict__ A2p, const unsigned short* __restrict__ B2w,
             const float* __restrict__ bias2, void* __restrict__ C2)
{
    constexpr int LDA = (MODE == 3) ? 2048 : 1024;
    constexpr int LDB = (MODE == 3) ? 2048 : 1024;
    const int bx = blockIdx.x, by = blockIdx.y, bz = blockIdx.z;
    if (MODE == 2 && bx > by) return;

    const unsigned short* A;
    const unsigned short* Bm;
    const float* bias = nullptr;
    int len, qy = 0, seg = 0, nsp = 1;
    if (MODE == 0) {
        A    = (bz == 0 ? A0p : bz == 1 ? A1p : A2p) + (size_t)by * 256 * LDA;
        Bm   = (bz == 0 ? B0w : bz == 1 ? B1w : B2w) + (size_t)bx * 256 * LDB;
        bias = bz == 0 ? bias0 : bz == 1 ? bias1 : bias2;
        len  = 1024;
    } else if (MODE == 2) {
        A   = A0p + (size_t)bz * SS * DD + (size_t)by * 256 * LDA;
        Bm  = B0w + (size_t)bz * SS * DD + (size_t)bx * 256 * LDB;
        len = 1024;
    } else {
        if (by < 4) { qy = by; seg = 0; nsp = 1; }
        else        { qy = 4 + ((by - 4) >> 1); seg = (by - 4) & 1; nsp = 2; }
        int ktot = (qy + 1) * 256, halfk = ktot >> 1;
        int kst = seg ? halfk : 0;
        len = (nsp == 1) ? ktot : halfk;
        A  = A0p + (size_t)bz * SS * SS + (size_t)qy * 256 * LDA + kst;
        Bm = B0w + (size_t)bz * DD * SS + (size_t)bx * 256 * LDB + kst;
    }

    extern __shared__ __align__(16) char lds[];
    const int tid = threadIdx.x;
    const int l = tid & 63, w = tid >> 6;
    const int wr = w >> 2, wc = w & 3;

    // stage one half-tile (2 x gload16/thread); LDS dest linear; global src
    // pre-swizzled (slot = col ^ (row&7)) so swizzled reads see linear data
    auto stg = [&](const unsigned short* src, int ld, char* mb, int half, int tile) {
        #pragma unroll
        for (int j = 0; j < 2; ++j) {
            int rr = half * 128 + (w * 2 + j) * 8 + (l >> 3);
            int cc = (l & 7) ^ (l >> 3);
            gload_lds16(src + (size_t)rr * ld + tile * 64 + cc * 8,
                        mb + half * 16384 + (w * 2 + j) * 1024);
        }
    };
    auto rdA = [&](int buf, int fm, int ks) -> bf8 {
        int row = wr * 128 + fm * 16 + (l & 15);
        return *(const bf8*)(lds + buf * 65536 + row * 128 +
                             ((((ks << 2) + (l >> 4)) ^ (l & 7)) << 4));
    };
    auto rdB = [&](int buf, int fn, int ks) -> bf8 {
        int row = wc * 64 + fn * 16 + (l & 15);
        return *(const bf8*)(lds + buf * 65536 + 32768 + row * 128 +
                             ((((ks << 2) + (l >> 4)) ^ (l & 7)) << 4));
    };

    char* A0b = lds;                 char* B0b = lds + 32768;
    char* A1b = lds + 65536;         char* B1b = lds + 98304;

    f32x4 acc[8][4];
    #pragma unroll
    for (int i2 = 0; i2 < 8; ++i2)
        #pragma unroll
        for (int j2 = 0; j2 < 4; ++j2) acc[i2][j2] = (f32x4){0.f, 0.f, 0.f, 0.f};

    bf8 aA[4][2], aB[4][2], bL[2][2], bH[2][2];

    const int NT = len >> 6;
    // prologue: tile0 full -> buf0, tile1 A-halves -> buf1
    stg(A, LDA, A0b, 0, 0);  stg(A, LDA, A0b, 1, 0);
    stg(Bm, LDB, B0b, 0, 0); stg(Bm, LDB, B0b, 1, 0);
    stg(A, LDA, A1b, 0, 1);  stg(A, LDA, A1b, 1, 1);
    VMW(4); BAR();

    for (int it = 0; it < NT / 2 - 1; ++it) {
        const int t1o = 2 * it + 1, t2 = 2 * it + 2, t3 = 2 * it + 3;
        // p0
        LDA4(0, 0, aA); LDB2(0, 0, bL);
        stg(Bm, LDB, B1b, 0, t1o);
        LGKM8(); BAR(); LGKM0();
        P1(); QUAD(0, 0, aA, bL); P0();
        BAR();
        // p1
        LDA4(0, 4, aB);
        stg(Bm, LDB, B1b, 1, t1o);
        BAR(); LGKM0();
        P1(); QUAD(4, 0, aB, bL); P0();
        BAR();
        // p2
        LDB2(0, 2, bH);
        stg(A, LDA, A0b, 0, t2);
        BAR(); LGKM0();
        P1(); QUAD(4, 2, aB, bH); P0();
        BAR();
        // p3 (+vmcnt(4): tile t1o fully landed for p4-p7)
        stg(A, LDA, A0b, 1, t2);
        BAR();
        P1(); QUAD(0, 2, aA, bH); P0();
        VMW(4); BAR();
        // p4
        LDA4(1, 0, aA); LDB2(1, 0, bL);
        stg(Bm, LDB, B0b, 0, t2);
        LGKM8(); BAR(); LGKM0();
        P1(); QUAD(0, 0, aA, bL); P0();
        BAR();
        // p5
        LDA4(1, 4, aB);
        stg(Bm, LDB, B0b, 1, t2);
        BAR(); LGKM0();
        P1(); QUAD(4, 0, aB, bL); P0();
        BAR();
        // p6
        LDB2(1, 2, bH);
        stg(A, LDA, A1b, 0, t3);
        BAR(); LGKM0();
        P1(); QUAD(4, 2, aB, bH); P0();
        BAR();
        // p7 (+vmcnt(4): tile t2 fully landed for next-iter p0-p3)
        stg(A, LDA, A1b, 1, t3);
        BAR();
        P1(); QUAD(0, 2, aA, bH); P0();
        VMW(4); BAR();
    }

    // ---- peeled tail: K-tiles NT-2 (buf0) and NT-1 (buf1) ----
    const int tl = NT - 1;
    LDA4(0, 0, aA); LDB2(0, 0, bL);
    stg(Bm, LDB, B1b, 0, tl);
    stg(Bm, LDB, B1b, 1, tl);
    LDA4(0, 4, aB); LDB2(0, 2, bH);
    P1();
    QUAD(0, 0, aA, bL); QUAD(4, 0, aB, bL); QUAD(4, 2, aB, bH); QUAD(0, 2, aA, bH);
    P0();
    VMW(0); BAR();
    LDA4(1, 0, aA); LDB2(1, 0, bL); LDA4(1, 4, aB); LDB2(1, 2, bH);
    P1();
    QUAD(0, 0, aA, bL); QUAD(4, 0, aB, bL); QUAD(4, 2, aB, bH); QUAD(0, 2, aA, bH);
    P0();

    // ---- epilogue ----
    const int mb0 = ((MODE == 3) ? qy * 256 : by * 256) + wr * 128;
    const int nb0 = bx * 256 + wc * 64;
    if (MODE == 0) {
        float bv[4];
        #pragma unroll
        for (int fn = 0; fn < 4; ++fn) bv[fn] = bias[nb0 + fn * 16 + (l & 15)];
        if (bz < 2) {
            unsigned short* C = (unsigned short*)(bz == 0 ? C0 : C1);
            #pragma unroll
            for (int fm = 0; fm < 8; ++fm) {
                int m0 = mb0 + fm * 16 + ((l >> 4) << 2);
                #pragma unroll
                for (int fn = 0; fn < 4; ++fn) {
                    int n = nb0 + fn * 16 + (l & 15);
                    #pragma unroll
                    for (int r = 0; r < 4; ++r)
                        C[(size_t)(m0 + r) * DD + n] = f2bf(acc[fm][fn][r] + bv[fn]);
                }
            }
        } else {
            unsigned short* C = (unsigned short*)C2;
            int batch = (by * 256) >> 11;
            int sbase = by * 256 - batch * SS + wr * 128;
            #pragma unroll
            for (int fm = 0; fm < 8; ++fm) {
                int s0 = sbase + fm * 16 + ((l >> 4) << 2);
                #pragma unroll
                for (int fn = 0; fn < 4; ++fn) {
                    int n = nb0 + fn * 16 + (l & 15);
                    ushort4 pk;
                    pk.x = f2bf(acc[fm][fn][0] + bv[fn]);
                    pk.y = f2bf(acc[fm][fn][1] + bv[fn]);
                    pk.z = f2bf(acc[fm][fn][2] + bv[fn]);
                    pk.w = f2bf(acc[fm][fn][3] + bv[fn]);
                    *(ushort4*)&C[(size_t)batch * DD * SS + (size_t)n * SS + s0] = pk;
                }
            }
        }
    } else if (MODE == 2) {
        float* C = (float*)C0 + (size_t)bz * SS * SS;
        #pragma unroll
        for (int fm = 0; fm < 8; ++fm) {
            int m0 = mb0 + fm * 16 + ((l >> 4) << 2);
            #pragma unroll
            for (int fn = 0; fn < 4; ++fn) {
                int n = nb0 + fn * 16 + (l & 15);
                #pragma unroll
                for (int r = 0; r < 4; ++r)
                    C[(size_t)(m0 + r) * SS + n] = acc[fm][fn][r] * 0.03125f;
            }
        }
    } else {
        float* C = (float*)C0 + (size_t)bz * SS * DD;
        #pragma unroll
        for (int fm = 0; fm < 8; ++fm) {
            int m0 = mb0 + fm * 16 + ((l >> 4) << 2);
            #pragma unroll
            for (int fn = 0; fn < 4; ++fn) {
                int n = nb0 + fn * 16 + (l & 15);
                if (nsp == 1) {
                    #pragma unroll
                    for (int r = 0; r < 4; ++r)
                        C[(size_t)(m0 + r) * DD + n] = acc[fm][fn][r];
                } else {
                    #pragma unroll
                    for (int r = 0; r < 4; ++r)
                        atomicAdd(&C[(size_t)(m0 + r) * DD + n], acc[fm][fn][r]);
                }
            }
        }
    }
}

// ---------------- causal row softmax: fp32 scores -> bf16 P ----------------
__global__ __launch_bounds__(256)
void softmax_causal(const float* __restrict__ Sb, unsigned short* __restrict__ P) {
    __shared__ float tmp[8];
    int row = blockIdx.x;
    int b = row >> 11, q = row & 2047;
    const float* s = Sb + ((size_t)b * SS + q) * SS;
    unsigned short* p = P + ((size_t)b * SS + q) * SS;
    int len  = q + 1;
    int wlen = ((q >> 8) + 1) << 8;            // zero-pad to 256 for PV tiles

    float mx = -3e38f;
    for (int i = threadIdx.x; i < len; i += 256) mx = fmaxf(mx, s[i]);
    #pragma unroll
    for (int o = 32; o; o >>= 1) mx = fmaxf(mx, __shfl_xor(mx, o));
    if ((threadIdx.x & 63) == 0) tmp[threadIdx.x >> 6] = mx;
    __syncthreads();
    mx = fmaxf(fmaxf(tmp[0], tmp[1]), fmaxf(tmp[2], tmp[3]));

    float sum = 0.f;
    for (int i = threadIdx.x; i < len; i += 256) sum += __expf(s[i] - mx);
    #pragma unroll
    for (int o = 32; o; o >>= 1) sum += __shfl_xor(sum, o);
    if ((threadIdx.x & 63) == 0) tmp[4 + (threadIdx.x >> 6)] = sum;
    __syncthreads();
    sum = tmp[4] + tmp[5] + tmp[6] + tmp[7];
    float inv = 1.f / sum;

    for (int i = threadIdx.x; i < wlen; i += 256) {
        float e = (i < len) ? __expf(s[i] - mx) * inv : 0.f;
        p[i] = f2bf(e);
    }
}

// ---------------- launch ----------------
extern "C" void kernel_launch(void* const* d_in, const int* in_sizes, int n_in,
                              void* d_out, int out_size, void* d_ws, size_t ws_size,
                              hipStream_t stream) {
    constexpr size_t NX = (size_t)NB * SS * DD;
    constexpr size_t NW = (size_t)DD * DD;

    const float* q   = (const float*)d_in[0];
    const float* k   = (const float*)d_in[1];
    const float* v   = (const float*)d_in[2];
    const float* w_q = (const float*)d_in[4];
    const float* b_q = (const float*)d_in[5];
    const float* w_k = (const float*)d_in[6];
    const float* b_k = (const float*)d_in[7];
    const float* w_v = (const float*)d_in[8];
    const float* b_v = (const float*)d_in[9];
    float* out = (float*)d_out;

    char* ws = (char*)d_ws;
    size_t off = 0;
    auto take = [&](size_t bytes) { char* p = ws + off; off += (bytes + 255) & ~(size_t)255; return p; };
    unsigned short* qb  = (unsigned short*)take(NX * 2);
    unsigned short* kb  = (unsigned short*)take(NX * 2);
    unsigned short* vb  = (unsigned short*)take(NX * 2);
    unsigned short* wqb = (unsigned short*)take(NW * 2);
    unsigned short* wkb = (unsigned short*)take(NW * 2);
    unsigned short* wvb = (unsigned short*)take(NW * 2);
    unsigned short* Qp  = (unsigned short*)take(NX * 2);
    unsigned short* Kp  = (unsigned short*)take(NX * 2);
    unsigned short* VpT = (unsigned short*)take(NX * 2);   // [b][d][s]
    float*          Sb  = (float*)take((size_t)NB * SS * SS * 4);
    unsigned short* P   = qb;   // 33.5 MB: overlays dead qb+kb after projections

    dim3 blk(256);
    cvt3<<<dim3(NX / 4 / 256, 3), blk, 0, stream>>>(q, k, v, qb, kb, vb, (int)(NX / 4));
    cvt3<<<dim3(NW / 4 / 256, 3), blk, 0, stream>>>(w_q, w_k, w_v, wqb, wkb, wvb, (int)(NW / 4));
    hipMemsetAsync(d_out, 0, NB * (size_t)SS * DD * 4, stream);  // PV split-K accumulates

    constexpr size_t LDSB = 131072;
    gemm256<0><<<dim3(4, 32, 3), dim3(512), LDSB, stream>>>(
        qb, wqb, b_q, Qp,  kb, wkb, b_k, Kp,  vb, wvb, b_v, VpT);
    gemm256<2><<<dim3(8, 8, 4), dim3(512), LDSB, stream>>>(
        Qp, Kp, nullptr, Sb, nullptr, nullptr, nullptr, nullptr,
        nullptr, nullptr, nullptr, nullptr);
    softmax_causal<<<dim3(NB * SS), blk, 0, stream>>>(Sb, P);
    gemm256<3><<<dim3(4, 12, 4), dim3(512), LDSB, stream>>>(
        P, VpT, nullptr, out, nullptr, nullptr, nullptr, nullptr,
        nullptr, nullptr, nullptr, nullptr);
}

// Round 5
// 219.399 us; speedup vs baseline: 1.9233x; 1.3550x over previous
//
#include <hip/hip_runtime.h>
#include <hip/hip_bf16.h>

// B=4, S=2048, D=1024; fp32 in/out, bf16 MFMA compute.
// R5: proven R1 128x128/BK=32 m97-structure engine everywhere;
// merged QKV proj dispatch, split-K PV (balance), XCD swizzle, fast softmax.
#define SS 2048
#define DD 1024
#define NB 4

typedef __attribute__((ext_vector_type(8))) short  bf8;    // 8 x bf16
typedef __attribute__((ext_vector_type(4))) float  f32x4;

static __device__ __forceinline__ unsigned short f2bf(float f) {
    unsigned u = __float_as_uint(f);
    u += 0x7fffu + ((u >> 16) & 1u);          // round-to-nearest-even
    return (unsigned short)(u >> 16);
}

static __device__ __forceinline__ void gload_lds16(const void* g, void* lds) {
    __builtin_amdgcn_global_load_lds((__attribute__((address_space(1))) void*)g,
                                     (__attribute__((address_space(3))) void*)lds,
                                     16, 0, 0);
}

// ---------------- fp32 -> bf16 converts ----------------
__global__ __launch_bounds__(256)
void cvt3(const float* __restrict__ a, const float* __restrict__ b, const float* __restrict__ c,
          unsigned short* __restrict__ oa, unsigned short* __restrict__ ob,
          unsigned short* __restrict__ oc, int n4) {
    int i = blockIdx.x * 256 + threadIdx.x;
    if (i >= n4) return;
    const float* in = blockIdx.y == 0 ? a : blockIdx.y == 1 ? b : c;
    unsigned short* out = blockIdx.y == 0 ? oa : blockIdx.y == 1 ? ob : oc;
    float4 v = ((const float4*)in)[i];
    ushort4 o;
    o.x = f2bf(v.x); o.y = f2bf(v.y); o.z = f2bf(v.z); o.w = f2bf(v.w);
    ((ushort4*)out)[i] = o;
}

// ---------------- 128x128 BK=32 bt-GEMM (R1/m97 structure) ----------------
// MODE 0: merged QKV proj; z = which proj; z==2 stores transposed [b][d][s]
// MODE 2: scores = Q.K^T/32, fp32, causal tile skip
// MODE 3: PV, fp32 out, causal K-limit, 2-way split-K for qt>=8 (atomicAdd)
#define BM 128
#define BN 128
#define BK 32

template<int MODE>
__global__ __launch_bounds__(256, 2)
void gemm_bt(const unsigned short* __restrict__ A0p, const unsigned short* __restrict__ B0p,
             const float* __restrict__ bias0,
             const unsigned short* __restrict__ A1p, const unsigned short* __restrict__ B1p,
             const float* __restrict__ bias1,
             const unsigned short* __restrict__ A2p, const unsigned short* __restrict__ B2p,
             const float* __restrict__ bias2,
             void* __restrict__ Cout)
{
    constexpr int LDA = (MODE == 3) ? 2048 : 1024;
    constexpr int LDB = (MODE == 3) ? 2048 : 1024;
    constexpr int GX  = (MODE == 2) ? 16 : 8;            // grid x size
    constexpr int NWG = (MODE == 0) ? 512 : (MODE == 2) ? 256 : 192; // per z
    constexpr int CPX = NWG >> 3;                        // chunk per XCD

    // bijective XCD swizzle (T1, m204): consecutive remapped blocks share an XCD
    int bx, by;
    {
        int f  = (int)blockIdx.y * GX + (int)blockIdx.x;
        int f2 = (f & 7) * CPX + (f >> 3);
        bx = f2 % GX; by = f2 / GX;
    }
    const int bz = blockIdx.z;
    if (MODE == 2 && bx > by) return;                    // fully-masked causal tile

    const unsigned short* A;
    const unsigned short* Bm;
    const float* bias = nullptr;
    int len, qt = 0, nsp = 1;
    if (MODE == 0) {
        A    = (bz == 0 ? A0p : bz == 1 ? A1p : A2p) + (size_t)by * BM * LDA;
        Bm   = (bz == 0 ? B0p : bz == 1 ? B1p : B2p) + (size_t)bx * BN * LDB;
        bias = bz == 0 ? bias0 : bz == 1 ? bias1 : bias2;
        len  = 1024;
    } else if (MODE == 2) {
        A   = A0p + (size_t)bz * SS * DD + (size_t)by * BM * LDA;
        Bm  = B0p + (size_t)bz * SS * DD + (size_t)bx * BN * LDB;
        len = 1024;
    } else {
        int seg = 0;
        if (by < 8) { qt = by; nsp = 1; }
        else        { qt = 8 + ((by - 8) >> 1); seg = (by - 8) & 1; nsp = 2; }
        int ktot = (qt + 1) * 128, hk = ktot >> 1;
        int kst  = (nsp == 2 && seg) ? hk : 0;
        len = (nsp == 1) ? ktot : hk;
        A  = A0p + (size_t)bz * SS * SS + (size_t)qt * BM * LDA + kst;
        Bm = B0p + (size_t)bz * DD * SS + (size_t)bx * BN * LDB + kst;
    }

    __shared__ __align__(16) unsigned short As[BM * BK];
    __shared__ __align__(16) unsigned short Bs[BN * BK];

    const int t = threadIdx.x;
    const int l = t & 63;
    const int w = t >> 6;
    const int wr = w >> 1, wc = w & 1;

    const int c0 = t, c1 = t + 256;
    const int r0 = c0 >> 2, k0 = (c0 & 3) * 8;
    const int r1 = c1 >> 2, k1 = (c1 & 3) * 8;

    f32x4 zero = {0.f, 0.f, 0.f, 0.f};
    f32x4 acc[4][4];
    #pragma unroll
    for (int i = 0; i < 4; i++)
        #pragma unroll
        for (int j = 0; j < 4; j++) acc[i][j] = zero;

    const int ar = wr * 64 + (l & 15);
    const int br = wc * 64 + (l & 15);
    const int kc = (l >> 4) * 8;

    for (int kk = 0; kk < len; kk += BK) {
        gload_lds16(A + (size_t)r0 * LDA + kk + k0, &As[c0 * 8]);
        gload_lds16(A + (size_t)r1 * LDA + kk + k1, &As[c1 * 8]);
        gload_lds16(Bm + (size_t)r0 * LDB + kk + k0, &Bs[c0 * 8]);
        gload_lds16(Bm + (size_t)r1 * LDB + kk + k1, &Bs[c1 * 8]);
        __syncthreads();
        bf8 af[4], bfr[4];
        #pragma unroll
        for (int i = 0; i < 4; i++) af[i]  = *(const bf8*)&As[(ar + i * 16) * BK + kc];
        #pragma unroll
        for (int j = 0; j < 4; j++) bfr[j] = *(const bf8*)&Bs[(br + j * 16) * BK + kc];
        #pragma unroll
        for (int i = 0; i < 4; i++)
            #pragma unroll
            for (int j = 0; j < 4; j++)
                acc[i][j] = __builtin_amdgcn_mfma_f32_16x16x32_bf16(af[i], bfr[j], acc[i][j], 0, 0, 0);
        __syncthreads();
    }

    const int mb = ((MODE == 3) ? qt : by) * BM + wr * 64;
    const int nb = bx * BN + wc * 64;

    if (MODE == 0) {
        float bv[4];
        #pragma unroll
        for (int j = 0; j < 4; j++) bv[j] = bias[nb + j * 16 + (l & 15)];
        if (bz < 2) {
            unsigned short* C = (unsigned short*)Cout + (size_t)bz * NB * SS * DD;
            #pragma unroll
            for (int i = 0; i < 4; i++) {
                int m0 = mb + i * 16 + ((l >> 4) << 2);
                #pragma unroll
                for (int j = 0; j < 4; j++) {
                    int n = nb + j * 16 + (l & 15);
                    #pragma unroll
                    for (int r = 0; r < 4; r++)
                        C[(size_t)(m0 + r) * DD + n] = f2bf(acc[i][j][r] + bv[j]);
                }
            }
        } else {
            // V: per-batch transposed store C[b][n][s]
            unsigned short* C = (unsigned short*)Cout + (size_t)2 * NB * SS * DD;
            int batch = (by * BM) >> 11;
            #pragma unroll
            for (int i = 0; i < 4; i++) {
                int s = (mb - batch * SS) + i * 16 + ((l >> 4) << 2);
                #pragma unroll
                for (int j = 0; j < 4; j++) {
                    int n = nb + j * 16 + (l & 15);
                    ushort4 pk;
                    pk.x = f2bf(acc[i][j][0] + bv[j]);
                    pk.y = f2bf(acc[i][j][1] + bv[j]);
                    pk.z = f2bf(acc[i][j][2] + bv[j]);
                    pk.w = f2bf(acc[i][j][3] + bv[j]);
                    *(ushort4*)&C[(size_t)batch * DD * SS + (size_t)n * SS + s] = pk;
                }
            }
        }
    } else if (MODE == 2) {
        float* C = (float*)Cout + (size_t)bz * SS * SS;
        #pragma unroll
        for (int i = 0; i < 4; i++) {
            int m0 = mb + i * 16 + ((l >> 4) << 2);
            #pragma unroll
            for (int j = 0; j < 4; j++) {
                int n = nb + j * 16 + (l & 15);
                #pragma unroll
                for (int r = 0; r < 4; r++)
                    C[(size_t)(m0 + r) * SS + n] = acc[i][j][r] * 0.03125f;
            }
        }
    } else {
        float* C = (float*)Cout + (size_t)bz * SS * DD;
        #pragma unroll
        for (int i = 0; i < 4; i++) {
            int m0 = mb + i * 16 + ((l >> 4) << 2);
            #pragma unroll
            for (int j = 0; j < 4; j++) {
                int n = nb + j * 16 + (l & 15);
                if (nsp == 1) {
                    #pragma unroll
                    for (int r = 0; r < 4; r++)
                        C[(size_t)(m0 + r) * DD + n] = acc[i][j][r];
                } else {
                    #pragma unroll
                    for (int r = 0; r < 4; r++)
                        atomicAdd(&C[(size_t)(m0 + r) * DD + n], acc[i][j][r]);
                }
            }
        }
    }
}

// ---------------- causal row softmax: fp32 scores -> bf16 P (float4) ----------------
__global__ __launch_bounds__(256)
void softmax_causal(const float* __restrict__ Sb, unsigned short* __restrict__ P) {
    __shared__ float tmp[8];
    int row = blockIdx.x;
    int b = row >> 11, q = row & 2047;
    const float* s = Sb + ((size_t)b * SS + q) * SS;
    unsigned short* p = P + ((size_t)b * SS + q) * SS;
    int len  = q + 1;
    int len4 = len >> 2;
    int wlen = ((q >> 7) + 1) << 7;            // zero-pad to 128 for PV tiles

    float mx = -3e38f;
    for (int i = threadIdx.x; i < len4; i += 256) {
        float4 v = ((const float4*)s)[i];
        mx = fmaxf(fmaxf(fmaxf(mx, v.x), v.y), fmaxf(v.z, v.w));
    }
    for (int i = (len4 << 2) + threadIdx.x; i < len; i += 256) mx = fmaxf(mx, s[i]);
    #pragma unroll
    for (int o = 32; o; o >>= 1) mx = fmaxf(mx, __shfl_xor(mx, o));
    if ((threadIdx.x & 63) == 0) tmp[threadIdx.x >> 6] = mx;
    __syncthreads();
    mx = fmaxf(fmaxf(tmp[0], tmp[1]), fmaxf(tmp[2], tmp[3]));

    float sum = 0.f;
    for (int i = threadIdx.x; i < len4; i += 256) {
        float4 v = ((const float4*)s)[i];
        sum += __expf(v.x - mx) + __expf(v.y - mx) + __expf(v.z - mx) + __expf(v.w - mx);
    }
    for (int i = (len4 << 2) + threadIdx.x; i < len; i += 256) sum += __expf(s[i] - mx);
    #pragma unroll
    for (int o = 32; o; o >>= 1) sum += __shfl_xor(sum, o);
    if ((threadIdx.x & 63) == 0) tmp[4 + (threadIdx.x >> 6)] = sum;
    __syncthreads();
    sum = tmp[4] + tmp[5] + tmp[6] + tmp[7];
    float inv = 1.f / sum;

    for (int i4 = threadIdx.x; i4 < (wlen >> 2); i4 += 256) {
        int i = i4 << 2;
        float4 v = ((const float4*)s)[i4];    // row fully allocated; mask below
        ushort4 o;
        o.x = (i     < len) ? f2bf(__expf(v.x - mx) * inv) : (unsigned short)0;
        o.y = (i + 1 < len) ? f2bf(__expf(v.y - mx) * inv) : (unsigned short)0;
        o.z = (i + 2 < len) ? f2bf(__expf(v.z - mx) * inv) : (unsigned short)0;
        o.w = (i + 3 < len) ? f2bf(__expf(v.w - mx) * inv) : (unsigned short)0;
        *(ushort4*)&p[i] = o;
    }
}

// ---------------- launch ----------------
extern "C" void kernel_launch(void* const* d_in, const int* in_sizes, int n_in,
                              void* d_out, int out_size, void* d_ws, size_t ws_size,
                              hipStream_t stream) {
    constexpr size_t NX = (size_t)NB * SS * DD;   // 8388608
    constexpr size_t NW = (size_t)DD * DD;        // 1048576

    const float* q   = (const float*)d_in[0];
    const float* k   = (const float*)d_in[1];
    const float* v   = (const float*)d_in[2];
    const float* w_q = (const float*)d_in[4];
    const float* b_q = (const float*)d_in[5];
    const float* w_k = (const float*)d_in[6];
    const float* b_k = (const float*)d_in[7];
    const float* w_v = (const float*)d_in[8];
    const float* b_v = (const float*)d_in[9];
    float* out = (float*)d_out;

    char* ws = (char*)d_ws;
    size_t off = 0;
    auto take = [&](size_t bytes) { char* p = ws + off; off += (bytes + 255) & ~(size_t)255; return p; };
    unsigned short* qb  = (unsigned short*)take(NX * 2);
    unsigned short* kb  = (unsigned short*)take(NX * 2);
    unsigned short* vb  = (unsigned short*)take(NX * 2);
    unsigned short* wqb = (unsigned short*)take(NW * 2);
    unsigned short* wkb = (unsigned short*)take(NW * 2);
    unsigned short* wvb = (unsigned short*)take(NW * 2);
    unsigned short* QKV = (unsigned short*)take(NX * 2 * 3);   // Qp | Kp | VpT contiguous
    float*          Sb  = (float*)take((size_t)NB * SS * SS * 4);
    unsigned short* Qp  = QKV;
    unsigned short* Kp  = QKV + NX;
    unsigned short* VpT = QKV + 2 * NX;           // [b][d][s]
    unsigned short* P   = qb;   // 33.5 MB: overlays dead qb+kb after projections

    dim3 blk(256);
    hipMemsetAsync(d_out, 0, NB * (size_t)SS * DD * 4, stream);  // PV split-K accumulates
    cvt3<<<dim3(NX / 4 / 256, 3), blk, 0, stream>>>(q, k, v, qb, kb, vb, (int)(NX / 4));
    cvt3<<<dim3(NW / 4 / 256, 3), blk, 0, stream>>>(w_q, w_k, w_v, wqb, wkb, wvb, (int)(NW / 4));

    // merged projections: M=8192, N=1024, K=1024; z = which proj
    gemm_bt<0><<<dim3(8, 64, 3), blk, 0, stream>>>(
        qb, wqb, b_q, kb, wkb, b_k, vb, wvb, b_v, QKV);

    // scores: per batch M=N=2048, K=1024, causal tile skip
    gemm_bt<2><<<dim3(16, 16, 4), blk, 0, stream>>>(
        Qp, Kp, nullptr, nullptr, nullptr, nullptr, nullptr, nullptr, nullptr, Sb);

    softmax_causal<<<dim3(NB * SS), blk, 0, stream>>>(Sb, P);

    // PV: per batch M=2048, N=1024, K=(qt+1)*128 with 2-way split for qt>=8
    gemm_bt<3><<<dim3(8, 24, 4), blk, 0, stream>>>(
        P, VpT, nullptr, nullptr, nullptr, nullptr, nullptr, nullptr, nullptr, out);
}